// Round 1
// baseline (3267.326 us; speedup 1.0000x reference)
//
#include <hip/hip_runtime.h>
#include <hip/hip_bf16.h>
#include <math.h>

#define N_NODE 30000
#define N_TRI  200000
#define DIM    128
#define OUTD   768
#define BATCH  2048
#define NROWA  4096
#define EPAD   30080   // 235*128, padded node count for GEMM tiles
#define GAMMA_C 3.0f
#define LAMB_C  30.0f
#define TAU_C   10.0f

typedef __attribute__((ext_vector_type(8))) __bf16 bf16x8;
typedef __attribute__((ext_vector_type(4))) float f32x4;

__device__ __forceinline__ float waveSum(float v){
#pragma unroll
  for (int m=1;m<64;m<<=1) v += __shfl_xor(v, m, 64);
  return v;
}

__device__ __forceinline__ void atomicMaxF(float* a, float v){
  if (v >= 0.f) atomicMax((int*)a, __float_as_int(v));
  else          atomicMin((unsigned int*)a, __float_as_uint(v));
}

// ---------------- fill ----------------
__global__ void k_fill(float* __restrict__ p, long n, float v){
  long i = (long)blockIdx.x*blockDim.x + threadIdx.x;
  long st = (long)gridDim.x*blockDim.x;
  for (; i<n; i+=st) p[i]=v;
}

// ---------------- sparse_mean accumulate ----------------
// one thread per (triple, dim): out[row*768 + d] += emb[col*128 + d]
__global__ __launch_bounds__(256) void k_spacc(const int* __restrict__ rows, const int* __restrict__ cols,
                        const float* __restrict__ emb, float* __restrict__ out, float* __restrict__ cnt){
  int g = blockIdx.x*256 + threadIdx.x;   // < 200000*128 = 25.6M
  int t = g>>7, d = g&127;
  int r = rows[t], c = cols[t];
  atomicAdd(out + (size_t)r*OUTD + d, emb[(size_t)c*DIM + d]);
  if (d==0) atomicAdd(cnt + r, 1.0f);
}

// mean + tanh for both e0 (off 0, cntE) and r0 (off 384, cntR)
__global__ __launch_bounds__(256) void k_meantanh(float* __restrict__ out, const float* __restrict__ cntE, const float* __restrict__ cntR){
  int g = blockIdx.x*256 + threadIdx.x;
  if (g >= N_NODE*DIM) return;
  int i = g>>7, d = g&127;
  float ce = fmaxf(cntE[i],1.f), cr = fmaxf(cntR[i],1.f);
  size_t be = (size_t)i*OUTD + d;
  out[be]       = tanhf(out[be]/ce);
  out[be + 384] = tanhf(out[be + 384]/cr);
}

// ---------------- tri_rel segment-sum ----------------
__global__ __launch_bounds__(256) void k_triacc(const int* __restrict__ ridx0, const int* __restrict__ ridx1,
                         const float* __restrict__ rval, const float* __restrict__ rel_emb,
                         float* __restrict__ tri){
  int g = blockIdx.x*256 + threadIdx.x;
  int t = g>>7, d = g&127;
  atomicAdd(tri + (size_t)ridx0[t]*DIM + d, rval[t]*rel_emb[(size_t)ridx1[t]*DIM + d]);
}

// normalize tri_rel rows in-place + compute 4 attention logit arrays
__global__ __launch_bounds__(256) void k_trinorm(float* __restrict__ tri, const float* __restrict__ attnE,
                                                 const float* __restrict__ attnR, float* __restrict__ att4){
  __shared__ float ak[4][DIM];
  int tid = threadIdx.x;
  for (int idx=tid; idx<4*DIM; idx+=256){
    int k = idx>>7, d = idx&127;
    ak[k][d] = (k<2) ? attnE[k*DIM + d] : attnR[(k-2)*DIM + d];
  }
  __syncthreads();
  int wave = tid>>6, lane = tid&63;
  int t = blockIdx.x*4 + wave;
  if (t >= N_TRI) return;
  float2 v = *(float2*)(tri + (size_t)t*DIM + lane*2);
  float ss = waveSum(v.x*v.x + v.y*v.y);
  float inv = 1.f/fmaxf(sqrtf(ss), 1e-12f);
  v.x *= inv; v.y *= inv;
  *(float2*)(tri + (size_t)t*DIM + lane*2) = v;
#pragma unroll
  for (int k=0;k<4;k++){
    float p = waveSum(v.x*ak[k][lane*2] + v.y*ak[k][lane*2+1]);
    if (lane==0) att4[(size_t)k*N_TRI + t] = p;
  }
}

// ---------------- GAT layer pieces ----------------
__global__ __launch_bounds__(256) void k_lprep(float* __restrict__ segmax, float* __restrict__ z){
  int i = blockIdx.x*256 + threadIdx.x;
  if (i < N_NODE){ segmax[i] = -1e30f; z[i] = 0.f; }
}

__global__ __launch_bounds__(256) void k_segmax(const int* __restrict__ rows, const float* __restrict__ att, float* __restrict__ segmax){
  int t = blockIdx.x*256 + threadIdx.x;
  if (t < N_TRI) atomicMaxF(segmax + rows[t], att[t]);
}

__global__ __launch_bounds__(256) void k_segexp(const int* __restrict__ rows, const float* __restrict__ att,
                       const float* __restrict__ segmax, float* __restrict__ ebuf, float* __restrict__ z){
  int t = blockIdx.x*256 + threadIdx.x;
  if (t < N_TRI){
    int r = rows[t];
    float e = expf(att[t] - segmax[r]);
    ebuf[t] = e;
    atomicAdd(z + r, e);
  }
}

// wave per triple: out[row, outoff..] += w * (f - 2*(f.u)*u), f = feats[col, inoff..]
__global__ __launch_bounds__(256) void k_scatter(const int* __restrict__ rows, const int* __restrict__ cols,
     const float* __restrict__ tri, const float* __restrict__ ebuf, const float* __restrict__ z,
     float* __restrict__ out, int inoff, int outoff){
  int wave = threadIdx.x>>6, lane = threadIdx.x&63;
  int t = blockIdx.x*4 + wave;
  if (t >= N_TRI) return;
  int r = rows[t], c = cols[t];
  float w = ebuf[t] / z[r];
  float2 u = *(const float2*)(tri + (size_t)t*DIM + lane*2);
  float2 f = *(const float2*)(out + (size_t)c*OUTD + inoff + lane*2);
  float dot = waveSum(f.x*u.x + f.y*u.y);
  float* dst = out + (size_t)r*OUTD + outoff + lane*2;
  atomicAdd(dst + 0, w*(f.x - 2.f*dot*u.x));
  atomicAdd(dst + 1, w*(f.y - 2.f*dot*u.y));
}

__global__ __launch_bounds__(256) void k_tanhslice(float* __restrict__ out, int off){
  int g = blockIdx.x*256 + threadIdx.x;
  if (g >= N_NODE*DIM) return;
  int i = g>>7, d = g&127;
  size_t b = (size_t)i*OUTD + off + d;
  out[b] = tanhf(out[b]);
}

// ---------------- loss prep ----------------
// wave per row j: bf16 convert + row sumsq; pad rows -> zeros
__global__ __launch_bounds__(256) void k_embbf16(const float* __restrict__ out, __bf16* __restrict__ E, float* __restrict__ esq){
  int wave = threadIdx.x>>6, lane = threadIdx.x&63;
  int j = blockIdx.x*4 + wave;
  if (j >= EPAD) return;
  if (j < N_NODE){
    float ss = 0.f;
#pragma unroll
    for (int c=0;c<12;c++){
      float v = out[(size_t)j*OUTD + c*64 + lane];
      ss += v*v;
      E[(size_t)j*OUTD + c*64 + lane] = (__bf16)v;
    }
    ss = waveSum(ss);
    if (lane==0) esq[j] = ss;
  } else {
#pragma unroll
    for (int c=0;c<12;c++) E[(size_t)j*OUTD + c*64 + lane] = (__bf16)0.f;
    if (lane==0) esq[j] = 0.f;
  }
}

// wave per pair: A rows (l at p, r at p+2048), pos, a_sq
__global__ __launch_bounds__(256) void k_buildA(const int* __restrict__ pairs, const __bf16* __restrict__ E,
    const float* __restrict__ out, const float* __restrict__ esq,
    __bf16* __restrict__ A, float* __restrict__ asq, float* __restrict__ pos){
  int wave = threadIdx.x>>6, lane = threadIdx.x&63;
  int p = blockIdx.x*4 + wave;
  if (p >= BATCH) return;
  int l = pairs[2*p], r = pairs[2*p+1];
  float ss = 0.f;
#pragma unroll
  for (int c=0;c<12;c++){
    int d = c*64 + lane;
    A[(size_t)p*OUTD + d]         = E[(size_t)l*OUTD + d];
    A[(size_t)(p+BATCH)*OUTD + d] = E[(size_t)r*OUTD + d];
    float dl = out[(size_t)l*OUTD + d], dr = out[(size_t)r*OUTD + d];
    ss += (dl-dr)*(dl-dr);
  }
  ss = waveSum(ss);
  if (lane==0){ pos[p] = ss; asq[p] = esq[l]; asq[p+BATCH] = esq[r]; }
}

// ---------------- fused GEMM + loss reductions ----------------
// tile: 128 i x 128 j per WG; wave w covers j in [w*32, w*32+32); MFMA 16x16x32 bf16
// pass 1: per-row Σ(loss-K), Σ(loss-K)^2, max(loss)   (K = pos + GAMMA, anti-cancellation shift)
// pass 2: per-row Σ exp(LAMB*(loss-mu)/sd + TAU - M)
__global__ __launch_bounds__(256) void k_gemm_loss(
    const __bf16* __restrict__ A, const __bf16* __restrict__ E,
    const float* __restrict__ asq, const float* __restrict__ esq,
    const float* __restrict__ pos, const int* __restrict__ pairs,
    float* __restrict__ rsum, float* __restrict__ rsq, float* __restrict__ rmax,
    const float* __restrict__ mu, const float* __restrict__ sd, const float* __restrict__ mm,
    float* __restrict__ rexp, int pass)
{
  __shared__ float lsum[128], lsq[128], lmax[128];
  int tid = threadIdx.x;
  if (tid < 128){ lsum[tid]=0.f; lsq[tid]=0.f; lmax[tid]=-1e30f; }
  __syncthreads();

  int wave = tid>>6, lane = tid&63, quad = lane>>4, l16 = lane&15;
  int i0 = blockIdx.y*128;
  int jw = blockIdx.x*128 + wave*32;

  const f32x4 zf = {0.f,0.f,0.f,0.f};
  f32x4 acc[8][2];
#pragma unroll
  for (int it=0; it<8; ++it){ acc[it][0]=zf; acc[it][1]=zf; }

  const __bf16* Ab = A + (size_t)(i0+l16)*OUTD + quad*8;
  const __bf16* Eb = E + (size_t)(jw+l16)*OUTD + quad*8;
  for (int k0=0; k0<OUTD; k0+=32){
    bf16x8 b0 = *(const bf16x8*)(Eb + k0);
    bf16x8 b1 = *(const bf16x8*)(Eb + (size_t)16*OUTD + k0);
#pragma unroll
    for (int it=0; it<8; ++it){
      bf16x8 a = *(const bf16x8*)(Ab + (size_t)it*16*OUTD + k0);
      acc[it][0] = __builtin_amdgcn_mfma_f32_16x16x32_bf16(a, b0, acc[it][0], 0,0,0);
      acc[it][1] = __builtin_amdgcn_mfma_f32_16x16x32_bf16(a, b1, acc[it][1], 0,0,0);
    }
  }

  // j-column info per lane (fixed across it/reg)
  int j0v = jw + l16, j1v = jw + 16 + l16;
  bool v0 = j0v < N_NODE, v1 = j1v < N_NODE;
  float esq0 = esq[j0v], esq1 = esq[j1v];

#pragma unroll
  for (int it=0; it<8; ++it){
#pragma unroll
    for (int reg=0; reg<4; ++reg){
      int i = i0 + it*16 + quad*4 + reg;
      int p = i & (BATCH-1);
      int li = pairs[2*p], ri = pairs[2*p+1];
      float posv = pos[p], av = asq[i];
      float Kv = posv + GAMMA_C;
      if (pass == 1){
        float s=0.f, q=0.f, mx=-1e30f;
        if (v0){
          float neg = av + esq0 - 2.f*acc[it][0][reg];
          float fct = 1.f - (j0v==li ? 1.f:0.f) - (j0v==ri ? 1.f:0.f);
          float loss = (Kv - neg)*fct;
          float x = loss - Kv;
          s += x; q += x*x; mx = fmaxf(mx, loss);
        }
        if (v1){
          float neg = av + esq1 - 2.f*acc[it][1][reg];
          float fct = 1.f - (j1v==li ? 1.f:0.f) - (j1v==ri ? 1.f:0.f);
          float loss = (Kv - neg)*fct;
          float x = loss - Kv;
          s += x; q += x*x; mx = fmaxf(mx, loss);
        }
#pragma unroll
        for (int m=1;m<16;m<<=1){
          s += __shfl_xor(s,m,64); q += __shfl_xor(q,m,64);
          mx = fmaxf(mx, __shfl_xor(mx,m,64));
        }
        if (l16 == 0){
          int il = it*16 + quad*4 + reg;
          atomicAdd(&lsum[il], s); atomicAdd(&lsq[il], q); atomicMaxF(&lmax[il], mx);
        }
      } else {
        float muv = mu[i], isd = 1.f/sd[i], Mv = mm[i];
        float s = 0.f;
        if (v0){
          float neg = av + esq0 - 2.f*acc[it][0][reg];
          float fct = 1.f - (j0v==li ? 1.f:0.f) - (j0v==ri ? 1.f:0.f);
          float loss = (Kv - neg)*fct;
          s += expf(LAMB_C*(loss-muv)*isd + TAU_C - Mv);
        }
        if (v1){
          float neg = av + esq1 - 2.f*acc[it][1][reg];
          float fct = 1.f - (j1v==li ? 1.f:0.f) - (j1v==ri ? 1.f:0.f);
          float loss = (Kv - neg)*fct;
          s += expf(LAMB_C*(loss-muv)*isd + TAU_C - Mv);
        }
#pragma unroll
        for (int m=1;m<16;m<<=1) s += __shfl_xor(s,m,64);
        if (l16 == 0) atomicAdd(&lsum[it*16 + quad*4 + reg], s);
      }
    }
  }
  __syncthreads();
  if (tid < 128){
    int i = i0 + tid;
    if (pass == 1){
      atomicAdd(rsum+i, lsum[tid]); atomicAdd(rsq+i, lsq[tid]); atomicMaxF(rmax+i, lmax[tid]);
    } else {
      atomicAdd(rexp+i, lsum[tid]);
    }
  }
}

__global__ __launch_bounds__(256) void k_stats(const float* __restrict__ rsum, const float* __restrict__ rsq,
                      const float* __restrict__ rmax, const float* __restrict__ pos,
                      float* __restrict__ mu, float* __restrict__ sd, float* __restrict__ mm){
  int i = blockIdx.x*256 + threadIdx.x;
  if (i >= NROWA) return;
  float K = pos[i & (BATCH-1)] + GAMMA_C;
  float a = rsum[i]*(1.f/N_NODE);
  float m = K + a;
  float v = rsq[i]*(1.f/N_NODE) - a*a;
  float s = sqrtf(fmaxf(v, 1e-30f));
  mu[i]=m; sd[i]=s;
  mm[i] = LAMB_C*(rmax[i]-m)/s + TAU_C;
}

__global__ __launch_bounds__(256) void k_final(const float* __restrict__ mm, const float* __restrict__ rexp, float* __restrict__ out){
  __shared__ float red[256];
  float s = 0.f;
  for (int i=threadIdx.x; i<NROWA; i+=256) s += mm[i] + logf(rexp[i]);
  red[threadIdx.x] = s; __syncthreads();
  for (int st=128; st>0; st>>=1){ if (threadIdx.x<st) red[threadIdx.x]+=red[threadIdx.x+st]; __syncthreads(); }
  if (threadIdx.x==0) out[0] = red[0]*(1.f/BATCH);
}

extern "C" void kernel_launch(void* const* d_in, const int* in_sizes, int n_in,
                              void* d_out, int out_size, void* d_ws, size_t ws_size,
                              hipStream_t stream) {
  const int*   pairs   = (const int*)d_in[0];
  const int*   ent_adj = (const int*)d_in[1];
  const int*   rel_adj = (const int*)d_in[2];
  const int*   adj     = (const int*)d_in[3];
  const int*   r_index = (const int*)d_in[4];
  const float* r_val   = (const float*)d_in[5];
  const float* ent_emb = (const float*)d_in[7];
  const float* rel_emb = (const float*)d_in[8];
  const float* attn_e  = (const float*)d_in[9];
  const float* attn_r  = (const float*)d_in[10];

  char* base = (char*)d_ws;
  size_t off = 0;
  auto take = [&](size_t bytes)->char*{
    char* p = base + off;
    off = (off + bytes + 511) & ~(size_t)511;
    return p;
  };
  float* OUT  = (float*)take((size_t)N_NODE*OUTD*4);   // 92.16 MB
  char*  TRIB = take((size_t)N_TRI*DIM*4);             // 102.4 MB, reused after GAT
  float* TRI  = (float*)TRIB;
  float* ATT4 = (float*)take((size_t)4*N_TRI*4);
  float* EBUF = (float*)take((size_t)N_TRI*4);
  float* CNTE = (float*)take((size_t)N_NODE*4);
  float* CNTR = (float*)take((size_t)N_NODE*4);
  float* SEGM = (float*)take((size_t)N_NODE*4);
  float* SEGZ = (float*)take((size_t)N_NODE*4);

  // overlay on TRI block (dead after GAT layers)
  size_t roff = 0;
  auto take2 = [&](size_t bytes)->char*{
    char* p = TRIB + roff;
    roff = (roff + bytes + 511) & ~(size_t)511;
    return p;
  };
  __bf16* EMBBF = (__bf16*)take2((size_t)EPAD*OUTD*2); // 46.2 MB
  float*  ESQ   = (float*)take2((size_t)EPAD*4);
  __bf16* ABF   = (__bf16*)take2((size_t)NROWA*OUTD*2);
  float*  ASQ   = (float*)take2((size_t)NROWA*4);
  float*  POS   = (float*)take2((size_t)BATCH*4);
  float*  RSUM  = (float*)take2((size_t)NROWA*4);
  float*  RSQ   = (float*)take2((size_t)NROWA*4);
  float*  RMAX  = (float*)take2((size_t)NROWA*4);
  float*  MU    = (float*)take2((size_t)NROWA*4);
  float*  SD    = (float*)take2((size_t)NROWA*4);
  float*  MM    = (float*)take2((size_t)NROWA*4);
  float*  REXP  = (float*)take2((size_t)NROWA*4);

  // ---- init ----
  k_fill<<<8192,256,0,stream>>>(OUT, (long)N_NODE*OUTD, 0.f);
  k_fill<<<8192,256,0,stream>>>(TRI, (long)N_TRI*DIM, 0.f);
  k_fill<<<64,256,0,stream>>>(CNTE, (long)N_NODE, 0.f);
  k_fill<<<64,256,0,stream>>>(CNTR, (long)N_NODE, 0.f);

  // ---- sparse means ----
  k_spacc<<<100000,256,0,stream>>>(ent_adj, ent_adj+N_TRI, ent_emb, OUT,       CNTE);
  k_spacc<<<100000,256,0,stream>>>(rel_adj, rel_adj+N_TRI, rel_emb, OUT+384,   CNTR);
  k_meantanh<<<15000,256,0,stream>>>(OUT, CNTE, CNTR);

  // ---- tri_rel + att logits ----
  k_triacc<<<100000,256,0,stream>>>(r_index, r_index+N_TRI, r_val, rel_emb, TRI);
  k_trinorm<<<50000,256,0,stream>>>(TRI, attn_e, attn_r, ATT4);

  // ---- 4 GAT layer instances: {attIdx, inoff, outoff} ----
  const int LATT[4]   = {0,   1,   2,   3};
  const int LIN[4]    = {0, 128, 384, 512};
  const int LOUTO[4]  = {128, 256, 512, 640};
  for (int L=0; L<4; ++L){
    const float* att = ATT4 + (size_t)LATT[L]*N_TRI;
    k_lprep  <<<118,256,0,stream>>>(SEGM, SEGZ);
    k_segmax <<<782,256,0,stream>>>(adj, att, SEGM);
    k_segexp <<<782,256,0,stream>>>(adj, att, SEGM, EBUF, SEGZ);
    k_scatter<<<50000,256,0,stream>>>(adj, adj+N_TRI, TRI, EBUF, SEGZ, OUT, LIN[L], LOUTO[L]);
    k_tanhslice<<<15000,256,0,stream>>>(OUT, LOUTO[L]);
  }

  // ---- loss prep (TRI block now reused) ----
  k_embbf16<<<7520,256,0,stream>>>(OUT, EMBBF, ESQ);
  k_buildA <<<512,256,0,stream>>>(pairs, EMBBF, OUT, ESQ, ABF, ASQ, POS);
  k_fill<<<16,256,0,stream>>>(RSUM, (long)NROWA, 0.f);
  k_fill<<<16,256,0,stream>>>(RSQ,  (long)NROWA, 0.f);
  k_fill<<<16,256,0,stream>>>(REXP, (long)NROWA, 0.f);
  k_fill<<<16,256,0,stream>>>(RMAX, (long)NROWA, -1e30f);

  // ---- fused GEMM + loss ----
  dim3 gg(EPAD/128, NROWA/128, 1);  // 235 x 32
  k_gemm_loss<<<gg,256,0,stream>>>(ABF, EMBBF, ASQ, ESQ, POS, pairs,
                                   RSUM, RSQ, RMAX, MU, SD, MM, REXP, 1);
  k_stats<<<16,256,0,stream>>>(RSUM, RSQ, RMAX, POS, MU, SD, MM);
  k_gemm_loss<<<gg,256,0,stream>>>(ABF, EMBBF, ASQ, ESQ, POS, pairs,
                                   RSUM, RSQ, RMAX, MU, SD, MM, REXP, 2);
  k_final<<<1,256,0,stream>>>(MM, REXP, (float*)d_out);
}

// Round 2
// 2018.384 us; speedup vs baseline: 1.6188x; 1.6188x over previous
//
#include <hip/hip_runtime.h>
#include <hip/hip_bf16.h>
#include <math.h>

#define N_NODE 30000
#define N_TRI  200000
#define DIM    128
#define OUTD   768
#define BATCH  2048
#define NROWA  4096
#define EPAD   30080   // 235*128, padded node count for GEMM tiles
#define NTILE_E 235
#define NTILE_A 32
#define TILE_ELEMS (128*OUTD)     // 98304 elements per 128-row tile
#define KBLK_ELEMS (128*32)       // 4096 elements per (128 x 32) k-block
#define GAMMA_C 3.0f
#define LAMB_C  30.0f
#define TAU_C   10.0f

typedef __attribute__((ext_vector_type(8))) __bf16 bf16x8;
typedef __attribute__((ext_vector_type(4))) float f32x4;

__device__ __forceinline__ float waveSum(float v){
#pragma unroll
  for (int m=1;m<64;m<<=1) v += __shfl_xor(v, m, 64);
  return v;
}

__device__ __forceinline__ void atomicMaxF(float* a, float v){
  if (v >= 0.f) atomicMax((int*)a, __float_as_int(v));
  else          atomicMin((unsigned int*)a, __float_as_uint(v));
}

__device__ __forceinline__ void gl2lds16(const void* g, void* l){
  __builtin_amdgcn_global_load_lds(
      (const __attribute__((address_space(1))) char*)g,
      (__attribute__((address_space(3))) char*)l, 16, 0, 0);
}

// swizzled 16B-chunk offset inside a (128 x 32) k-block: row r (0..127), logical chunk q (0..3)
__device__ __forceinline__ int swz_off(int r, int q){
  return r*32 + ((q ^ ((r>>1)&3))<<3);
}

// ---------------- fill ----------------
__global__ void k_fill(float* __restrict__ p, long n, float v){
  long i = (long)blockIdx.x*blockDim.x + threadIdx.x;
  long st = (long)gridDim.x*blockDim.x;
  for (; i<n; i+=st) p[i]=v;
}

// ---------------- sparse_mean accumulate ----------------
__global__ __launch_bounds__(256) void k_spacc(const int* __restrict__ rows, const int* __restrict__ cols,
                        const float* __restrict__ emb, float* __restrict__ out, float* __restrict__ cnt){
  int g = blockIdx.x*256 + threadIdx.x;   // < 200000*128 = 25.6M
  int t = g>>7, d = g&127;
  int r = rows[t], c = cols[t];
  atomicAdd(out + (size_t)r*OUTD + d, emb[(size_t)c*DIM + d]);
  if (d==0) atomicAdd(cnt + r, 1.0f);
}

__global__ __launch_bounds__(256) void k_meantanh(float* __restrict__ out, const float* __restrict__ cntE, const float* __restrict__ cntR){
  int g = blockIdx.x*256 + threadIdx.x;
  if (g >= N_NODE*DIM) return;
  int i = g>>7, d = g&127;
  float ce = fmaxf(cntE[i],1.f), cr = fmaxf(cntR[i],1.f);
  size_t be = (size_t)i*OUTD + d;
  out[be]       = tanhf(out[be]/ce);
  out[be + 384] = tanhf(out[be + 384]/cr);
}

// ---------------- tri_rel segment-sum ----------------
__global__ __launch_bounds__(256) void k_triacc(const int* __restrict__ ridx0, const int* __restrict__ ridx1,
                         const float* __restrict__ rval, const float* __restrict__ rel_emb,
                         float* __restrict__ tri){
  int g = blockIdx.x*256 + threadIdx.x;
  int t = g>>7, d = g&127;
  atomicAdd(tri + (size_t)ridx0[t]*DIM + d, rval[t]*rel_emb[(size_t)ridx1[t]*DIM + d]);
}

__global__ __launch_bounds__(256) void k_trinorm(float* __restrict__ tri, const float* __restrict__ attnE,
                                                 const float* __restrict__ attnR, float* __restrict__ att4){
  __shared__ float ak[4][DIM];
  int tid = threadIdx.x;
  for (int idx=tid; idx<4*DIM; idx+=256){
    int k = idx>>7, d = idx&127;
    ak[k][d] = (k<2) ? attnE[k*DIM + d] : attnR[(k-2)*DIM + d];
  }
  __syncthreads();
  int wave = tid>>6, lane = tid&63;
  int t = blockIdx.x*4 + wave;
  if (t >= N_TRI) return;
  float2 v = *(float2*)(tri + (size_t)t*DIM + lane*2);
  float ss = waveSum(v.x*v.x + v.y*v.y);
  float inv = 1.f/fmaxf(sqrtf(ss), 1e-12f);
  v.x *= inv; v.y *= inv;
  *(float2*)(tri + (size_t)t*DIM + lane*2) = v;
#pragma unroll
  for (int k=0;k<4;k++){
    float p = waveSum(v.x*ak[k][lane*2] + v.y*ak[k][lane*2+1]);
    if (lane==0) att4[(size_t)k*N_TRI + t] = p;
  }
}

// ---------------- GAT layer pieces ----------------
__global__ __launch_bounds__(256) void k_lprep(float* __restrict__ segmax, float* __restrict__ z){
  int i = blockIdx.x*256 + threadIdx.x;
  if (i < N_NODE){ segmax[i] = -1e30f; z[i] = 0.f; }
}

__global__ __launch_bounds__(256) void k_segmax(const int* __restrict__ rows, const float* __restrict__ att, float* __restrict__ segmax){
  int t = blockIdx.x*256 + threadIdx.x;
  if (t < N_TRI) atomicMaxF(segmax + rows[t], att[t]);
}

__global__ __launch_bounds__(256) void k_segexp(const int* __restrict__ rows, const float* __restrict__ att,
                       const float* __restrict__ segmax, float* __restrict__ ebuf, float* __restrict__ z){
  int t = blockIdx.x*256 + threadIdx.x;
  if (t < N_TRI){
    int r = rows[t];
    float e = expf(att[t] - segmax[r]);
    ebuf[t] = e;
    atomicAdd(z + r, e);
  }
}

__global__ __launch_bounds__(256) void k_scatter(const int* __restrict__ rows, const int* __restrict__ cols,
     const float* __restrict__ tri, const float* __restrict__ ebuf, const float* __restrict__ z,
     float* __restrict__ out, int inoff, int outoff){
  int wave = threadIdx.x>>6, lane = threadIdx.x&63;
  int t = blockIdx.x*4 + wave;
  if (t >= N_TRI) return;
  int r = rows[t], c = cols[t];
  float w = ebuf[t] / z[r];
  float2 u = *(const float2*)(tri + (size_t)t*DIM + lane*2);
  float2 f = *(const float2*)(out + (size_t)c*OUTD + inoff + lane*2);
  float dot = waveSum(f.x*u.x + f.y*u.y);
  float* dst = out + (size_t)r*OUTD + outoff + lane*2;
  atomicAdd(dst + 0, w*(f.x - 2.f*dot*u.x));
  atomicAdd(dst + 1, w*(f.y - 2.f*dot*u.y));
}

__global__ __launch_bounds__(256) void k_tanhslice(float* __restrict__ out, int off){
  int g = blockIdx.x*256 + threadIdx.x;
  if (g >= N_NODE*DIM) return;
  int i = g>>7, d = g&127;
  size_t b = (size_t)i*OUTD + off + d;
  out[b] = tanhf(out[b]);
}

// ---------------- loss prep: pack E into k-blocked swizzled tiles ----------------
// wave per row j. Ep layout: tile jt(128 rows) -> kb (24 blocks of 32k) -> row r -> swizzled 16B chunk
__global__ __launch_bounds__(256) void k_packE(const float* __restrict__ out, __bf16* __restrict__ Ep, float* __restrict__ esq){
  int wave = threadIdx.x>>6, lane = threadIdx.x&63;
  int j = blockIdx.x*4 + wave;
  if (j >= EPAD) return;
  int jt = j>>7, r = j&127;
  __bf16* tb = Ep + (size_t)jt*TILE_ELEMS;
  float ss = 0.f;
  for (int c=lane; c<96; c+=64){   // 96 chunks of 8 elements
    int kb = c>>2, q = c&3;
    bf16x8 o;
    if (j < N_NODE){
      const float* src = out + (size_t)j*OUTD + c*8;
#pragma unroll
      for (int e=0;e<8;e++){ float v = src[e]; ss += v*v; o[e] = (__bf16)v; }
    } else {
#pragma unroll
      for (int e=0;e<8;e++) o[e] = (__bf16)0.f;
    }
    *(bf16x8*)(tb + kb*KBLK_ELEMS + swz_off(r, q)) = o;
  }
  ss = waveSum(ss);
  if (lane==0) esq[j] = (j < N_NODE) ? ss : 0.f;
}

// wave per pair: build packed A rows (l at p, r at p+2048) by copying packed E chunks; pos & asq
__global__ __launch_bounds__(256) void k_packA(const int* __restrict__ pairs, const __bf16* __restrict__ Ep,
    const float* __restrict__ out, const float* __restrict__ esq,
    __bf16* __restrict__ Ap, float* __restrict__ asq, float* __restrict__ pos){
  int wave = threadIdx.x>>6, lane = threadIdx.x&63;
  int p = blockIdx.x*4 + wave;
  if (p >= BATCH) return;
  int l = pairs[2*p], r = pairs[2*p+1];
  float ss = 0.f;
#pragma unroll
  for (int c=0;c<12;c++){
    int d = c*64 + lane;
    float dl = out[(size_t)l*OUTD + d], dr = out[(size_t)r*OUTD + d];
    ss += (dl-dr)*(dl-dr);
  }
  ss = waveSum(ss);
  if (lane==0){ pos[p] = ss; asq[p] = esq[l]; asq[p+BATCH] = esq[r]; }
  // chunk copies
  int lt = l>>7, lr = l&127;
  int rt2 = r>>7, rr = r&127;
  int p0t = p>>7, p0r = p&127;
  int p1t = (p+BATCH)>>7, p1r = (p+BATCH)&127;
  for (int c=lane; c<96; c+=64){
    int kb = c>>2, q = c&3;
    bf16x8 vl = *(const bf16x8*)(Ep + (size_t)lt*TILE_ELEMS + kb*KBLK_ELEMS + swz_off(lr, q));
    *(bf16x8*)(Ap + (size_t)p0t*TILE_ELEMS + kb*KBLK_ELEMS + swz_off(p0r, q)) = vl;
    bf16x8 vr = *(const bf16x8*)(Ep + (size_t)rt2*TILE_ELEMS + kb*KBLK_ELEMS + swz_off(rr, q));
    *(bf16x8*)(Ap + (size_t)p1t*TILE_ELEMS + kb*KBLK_ELEMS + swz_off(p1r, q)) = vr;
  }
}

// ---------------- fused GEMM + loss (m97 structure) ----------------
// block = 128 i x 128 j, 4 waves each computing a 64x64 quadrant via 4x4 MFMA 16x16x32 frags.
// K-loop: stage (128x32)A + (128x32)B k-blocks to LDS via global_load_lds(16B), 24 steps.
__global__ __launch_bounds__(256) void k_gemm_loss(
    const __bf16* __restrict__ Ap, const __bf16* __restrict__ Ep,
    const float* __restrict__ asq, const float* __restrict__ esq,
    const float* __restrict__ pos, const int* __restrict__ pairs,
    float* __restrict__ rsum, float* __restrict__ rsq, float* __restrict__ rmax,
    const float* __restrict__ mu, const float* __restrict__ sd, const float* __restrict__ mm,
    float* __restrict__ rexp, int pass)
{
  __shared__ __bf16 sA[KBLK_ELEMS];
  __shared__ __bf16 sB[KBLK_ELEMS];
  __shared__ float lsum[128], lsq[128], lmax[128];
  int tid = threadIdx.x;
  if (tid < 128){ lsum[tid]=0.f; lsq[tid]=0.f; lmax[tid]=-1e30f; }

  int wave = tid>>6, lane = tid&63, quad = lane>>4, l16 = lane&15;
  int bi = blockIdx.y, bj = blockIdx.x;
  int wi = wave>>1, wj = wave&1;

  const __bf16* Asrc = Ap + (size_t)bi*TILE_ELEMS;
  const __bf16* Bsrc = Ep + (size_t)bj*TILE_ELEMS;

  // LDS fragment read offsets (elements), fixed across K-steps
  int a_off[4], b_off[4];
#pragma unroll
  for (int rt=0; rt<4; ++rt){ int row = wi*64 + rt*16 + l16; a_off[rt] = swz_off(row, quad); }
#pragma unroll
  for (int ct=0; ct<4; ++ct){ int row = wj*64 + ct*16 + l16; b_off[ct] = swz_off(row, quad); }

  // staging role: waves 0,1 -> A halves; waves 2,3 -> B halves. 4 x 1KB issues each.
  const __bf16* gsrc = (wave<2 ? Asrc : Bsrc);
  __bf16* ldsb = (wave<2 ? sA : sB);
  int half = (wave&1)*2048;   // elements

  const f32x4 zf = {0.f,0.f,0.f,0.f};
  f32x4 acc[4][4];
#pragma unroll
  for (int rt=0; rt<4; ++rt)
#pragma unroll
    for (int ct=0; ct<4; ++ct) acc[rt][ct] = zf;

  for (int kb=0; kb<24; ++kb){
    __syncthreads();
    const __bf16* g = gsrc + kb*KBLK_ELEMS + half + lane*8;
#pragma unroll
    for (int s=0; s<4; ++s)
      gl2lds16(g + s*512, ldsb + half + s*512);
    __syncthreads();
    bf16x8 af[4], bf[4];
#pragma unroll
    for (int rt=0; rt<4; ++rt) af[rt] = *(const bf16x8*)(sA + a_off[rt]);
#pragma unroll
    for (int ct=0; ct<4; ++ct) bf[ct] = *(const bf16x8*)(sB + b_off[ct]);
#pragma unroll
    for (int rt=0; rt<4; ++rt)
#pragma unroll
      for (int ct=0; ct<4; ++ct)
        acc[rt][ct] = __builtin_amdgcn_mfma_f32_16x16x32_bf16(af[rt], bf[ct], acc[rt][ct], 0,0,0);
  }

  // ---- loss epilogue ----
  int jbase = bj*128 + wj*64;
  float esqv[4]; bool val[4]; int jcol[4];
#pragma unroll
  for (int ct=0; ct<4; ++ct){
    jcol[ct] = jbase + ct*16 + l16;
    val[ct] = jcol[ct] < N_NODE;
    esqv[ct] = esq[jcol[ct]];
  }

#pragma unroll
  for (int rt=0; rt<4; ++rt){
#pragma unroll
    for (int reg=0; reg<4; ++reg){
      int il = wi*64 + rt*16 + quad*4 + reg;
      int i  = bi*128 + il;
      int p  = i & (BATCH-1);
      int li = pairs[2*p], ri = pairs[2*p+1];
      float Kv = pos[p] + GAMMA_C;
      float av = asq[i];
      if (pass == 1){
        float s=0.f, q=0.f, mx=-1e30f;
#pragma unroll
        for (int ct=0; ct<4; ++ct){
          if (val[ct]){
            float neg = av + esqv[ct] - 2.f*acc[rt][ct][reg];
            float fct = 1.f - (jcol[ct]==li ? 1.f:0.f) - (jcol[ct]==ri ? 1.f:0.f);
            float loss = (Kv - neg)*fct;
            float x = loss - Kv;
            s += x; q += x*x; mx = fmaxf(mx, loss);
          }
        }
#pragma unroll
        for (int m=1;m<16;m<<=1){
          s += __shfl_xor(s,m,64); q += __shfl_xor(q,m,64);
          mx = fmaxf(mx, __shfl_xor(mx,m,64));
        }
        if (l16 == 0){
          atomicAdd(&lsum[il], s); atomicAdd(&lsq[il], q); atomicMaxF(&lmax[il], mx);
        }
      } else {
        float muv = mu[i], isd = 1.f/sd[i], Mv = mm[i];
        float s = 0.f;
#pragma unroll
        for (int ct=0; ct<4; ++ct){
          if (val[ct]){
            float neg = av + esqv[ct] - 2.f*acc[rt][ct][reg];
            float fct = 1.f - (jcol[ct]==li ? 1.f:0.f) - (jcol[ct]==ri ? 1.f:0.f);
            float loss = (Kv - neg)*fct;
            s += expf(LAMB_C*(loss-muv)*isd + TAU_C - Mv);
          }
        }
#pragma unroll
        for (int m=1;m<16;m<<=1) s += __shfl_xor(s,m,64);
        if (l16 == 0) atomicAdd(&lsum[il], s);
      }
    }
  }
  __syncthreads();
  if (tid < 128){
    int i = bi*128 + tid;
    if (pass == 1){
      atomicAdd(rsum+i, lsum[tid]); atomicAdd(rsq+i, lsq[tid]); atomicMaxF(rmax+i, lmax[tid]);
    } else {
      atomicAdd(rexp+i, lsum[tid]);
    }
  }
}

__global__ __launch_bounds__(256) void k_stats(const float* __restrict__ rsum, const float* __restrict__ rsq,
                      const float* __restrict__ rmax, const float* __restrict__ pos,
                      float* __restrict__ mu, float* __restrict__ sd, float* __restrict__ mm){
  int i = blockIdx.x*256 + threadIdx.x;
  if (i >= NROWA) return;
  float K = pos[i & (BATCH-1)] + GAMMA_C;
  float a = rsum[i]*(1.f/N_NODE);
  float m = K + a;
  float v = rsq[i]*(1.f/N_NODE) - a*a;
  float s = sqrtf(fmaxf(v, 1e-30f));
  mu[i]=m; sd[i]=s;
  mm[i] = LAMB_C*(rmax[i]-m)/s + TAU_C;
}

__global__ __launch_bounds__(256) void k_final(const float* __restrict__ mm, const float* __restrict__ rexp, float* __restrict__ out){
  __shared__ float red[256];
  float s = 0.f;
  for (int i=threadIdx.x; i<NROWA; i+=256) s += mm[i] + logf(rexp[i]);
  red[threadIdx.x] = s; __syncthreads();
  for (int st=128; st>0; st>>=1){ if (threadIdx.x<st) red[threadIdx.x]+=red[threadIdx.x+st]; __syncthreads(); }
  if (threadIdx.x==0) out[0] = red[0]*(1.f/BATCH);
}

extern "C" void kernel_launch(void* const* d_in, const int* in_sizes, int n_in,
                              void* d_out, int out_size, void* d_ws, size_t ws_size,
                              hipStream_t stream) {
  const int*   pairs   = (const int*)d_in[0];
  const int*   ent_adj = (const int*)d_in[1];
  const int*   rel_adj = (const int*)d_in[2];
  const int*   adj     = (const int*)d_in[3];
  const int*   r_index = (const int*)d_in[4];
  const float* r_val   = (const float*)d_in[5];
  const float* ent_emb = (const float*)d_in[7];
  const float* rel_emb = (const float*)d_in[8];
  const float* attn_e  = (const float*)d_in[9];
  const float* attn_r  = (const float*)d_in[10];

  char* base = (char*)d_ws;
  size_t off = 0;
  auto take = [&](size_t bytes)->char*{
    char* p = base + off;
    off = (off + bytes + 511) & ~(size_t)511;
    return p;
  };
  float* OUT  = (float*)take((size_t)N_NODE*OUTD*4);   // 92.16 MB
  char*  TRIB = take((size_t)N_TRI*DIM*4);             // 102.4 MB, reused after GAT
  float* TRI  = (float*)TRIB;
  float* ATT4 = (float*)take((size_t)4*N_TRI*4);
  float* EBUF = (float*)take((size_t)N_TRI*4);
  float* CNTE = (float*)take((size_t)N_NODE*4);
  float* CNTR = (float*)take((size_t)N_NODE*4);
  float* SEGM = (float*)take((size_t)N_NODE*4);
  float* SEGZ = (float*)take((size_t)N_NODE*4);

  // overlay on TRI block (dead after GAT layers)
  size_t roff = 0;
  auto take2 = [&](size_t bytes)->char*{
    char* p = TRIB + roff;
    roff = (roff + bytes + 511) & ~(size_t)511;
    return p;
  };
  __bf16* EP    = (__bf16*)take2((size_t)NTILE_E*TILE_ELEMS*2); // 46.2 MB packed E
  float*  ESQ   = (float*)take2((size_t)EPAD*4);
  __bf16* AP    = (__bf16*)take2((size_t)NTILE_A*TILE_ELEMS*2); // 6.3 MB packed A
  float*  ASQ   = (float*)take2((size_t)NROWA*4);
  float*  POS   = (float*)take2((size_t)BATCH*4);
  float*  RSUM  = (float*)take2((size_t)NROWA*4);
  float*  RSQ   = (float*)take2((size_t)NROWA*4);
  float*  RMAX  = (float*)take2((size_t)NROWA*4);
  float*  MU    = (float*)take2((size_t)NROWA*4);
  float*  SD    = (float*)take2((size_t)NROWA*4);
  float*  MM    = (float*)take2((size_t)NROWA*4);
  float*  REXP  = (float*)take2((size_t)NROWA*4);

  // ---- init ----
  k_fill<<<8192,256,0,stream>>>(OUT, (long)N_NODE*OUTD, 0.f);
  k_fill<<<8192,256,0,stream>>>(TRI, (long)N_TRI*DIM, 0.f);
  k_fill<<<64,256,0,stream>>>(CNTE, (long)N_NODE, 0.f);
  k_fill<<<64,256,0,stream>>>(CNTR, (long)N_NODE, 0.f);

  // ---- sparse means ----
  k_spacc<<<100000,256,0,stream>>>(ent_adj, ent_adj+N_TRI, ent_emb, OUT,       CNTE);
  k_spacc<<<100000,256,0,stream>>>(rel_adj, rel_adj+N_TRI, rel_emb, OUT+384,   CNTR);
  k_meantanh<<<15000,256,0,stream>>>(OUT, CNTE, CNTR);

  // ---- tri_rel + att logits ----
  k_triacc<<<100000,256,0,stream>>>(r_index, r_index+N_TRI, r_val, rel_emb, TRI);
  k_trinorm<<<50000,256,0,stream>>>(TRI, attn_e, attn_r, ATT4);

  // ---- 4 GAT layer instances ----
  const int LIN[4]    = {0, 128, 384, 512};
  const int LOUTO[4]  = {128, 256, 512, 640};
  for (int L=0; L<4; ++L){
    const float* att = ATT4 + (size_t)L*N_TRI;
    k_lprep  <<<118,256,0,stream>>>(SEGM, SEGZ);
    k_segmax <<<782,256,0,stream>>>(adj, att, SEGM);
    k_segexp <<<782,256,0,stream>>>(adj, att, SEGM, EBUF, SEGZ);
    k_scatter<<<50000,256,0,stream>>>(adj, adj+N_TRI, TRI, EBUF, SEGZ, OUT, LIN[L], LOUTO[L]);
    k_tanhslice<<<15000,256,0,stream>>>(OUT, LOUTO[L]);
  }

  // ---- loss prep (TRI block now reused) ----
  k_packE<<<7520,256,0,stream>>>(OUT, EP, ESQ);
  k_packA<<<512,256,0,stream>>>(pairs, EP, OUT, ESQ, AP, ASQ, POS);
  k_fill<<<16,256,0,stream>>>(RSUM, (long)NROWA, 0.f);
  k_fill<<<16,256,0,stream>>>(RSQ,  (long)NROWA, 0.f);
  k_fill<<<16,256,0,stream>>>(REXP, (long)NROWA, 0.f);
  k_fill<<<16,256,0,stream>>>(RMAX, (long)NROWA, -1e30f);

  // ---- fused GEMM + loss ----
  dim3 gg(NTILE_E, NTILE_A, 1);  // 235 x 32
  k_gemm_loss<<<gg,256,0,stream>>>(AP, EP, ASQ, ESQ, POS, pairs,
                                   RSUM, RSQ, RMAX, MU, SD, MM, REXP, 1);
  k_stats<<<16,256,0,stream>>>(RSUM, RSQ, RMAX, POS, MU, SD, MM);
  k_gemm_loss<<<gg,256,0,stream>>>(AP, EP, ASQ, ESQ, POS, pairs,
                                   RSUM, RSQ, RMAX, MU, SD, MM, REXP, 2);
  k_final<<<1,256,0,stream>>>(MM, REXP, (float*)d_out);
}

// Round 3
// 1329.099 us; speedup vs baseline: 2.4583x; 1.5186x over previous
//
#include <hip/hip_runtime.h>
#include <hip/hip_bf16.h>
#include <math.h>

#define N_NODE 30000
#define N_TRI  200000
#define DIM    128
#define OUTD   768
#define BATCH  2048
#define NROWA  4096
#define EPAD   30080   // 235*128, padded node count for GEMM tiles
#define NTILE_E 235
#define NTILE_A 32
#define TILE_ELEMS (128*OUTD)     // 98304 elements per 128-row tile
#define KBLK_ELEMS (128*32)       // 4096 elements per (128 x 32) k-block
#define GAMMA_C 3.0f
#define LAMB_C  30.0f
#define TAU_C   10.0f

typedef __attribute__((ext_vector_type(8))) __bf16 bf16x8;
typedef __attribute__((ext_vector_type(4))) float f32x4;

__device__ __forceinline__ float waveSum(float v){
#pragma unroll
  for (int m=1;m<64;m<<=1) v += __shfl_xor(v, m, 64);
  return v;
}
__device__ __forceinline__ float waveMax(float v){
#pragma unroll
  for (int m=1;m<64;m<<=1) v = fmaxf(v, __shfl_xor(v, m, 64));
  return v;
}

__device__ __forceinline__ void atomicMaxF(float* a, float v){
  if (v >= 0.f) atomicMax((int*)a, __float_as_int(v));
  else          atomicMin((unsigned int*)a, __float_as_uint(v));
}

__device__ __forceinline__ void gl2lds16(const void* g, void* l){
  __builtin_amdgcn_global_load_lds(
      (const __attribute__((address_space(1))) char*)g,
      (__attribute__((address_space(3))) char*)l, 16, 0, 0);
}

// swizzled 16B-chunk offset inside a (128 x 32) k-block: row r (0..127), logical chunk q (0..3)
__device__ __forceinline__ int swz_off(int r, int q){
  return r*32 + ((q ^ ((r>>1)&3))<<3);
}

// ---------------- fill ----------------
__global__ void k_fill(float* __restrict__ p, long n, float v){
  long i = (long)blockIdx.x*blockDim.x + threadIdx.x;
  long st = (long)gridDim.x*blockDim.x;
  for (; i<n; i+=st) p[i]=v;
}

// ---------------- CSR build ----------------
__global__ __launch_bounds__(256) void k_hist(const int* __restrict__ rows, int* __restrict__ cnt){
  int t = blockIdx.x*256 + threadIdx.x;
  if (t < N_TRI) atomicAdd(&cnt[rows[t]], 1);
}

// one block per (cnt,rowptr) pair; exclusive scan of n=30000 + total at rowptr[n]
__global__ __launch_bounds__(256) void k_scan3(
    const int* __restrict__ c0, int* __restrict__ r0,
    const int* __restrict__ c1, int* __restrict__ r1,
    const int* __restrict__ c2, int* __restrict__ r2, int n){
  const int* cnt = blockIdx.x==0 ? c0 : (blockIdx.x==1 ? c1 : c2);
  int* rp        = blockIdx.x==0 ? r0 : (blockIdx.x==1 ? r1 : r2);
  __shared__ int buf[256];
  __shared__ int carry;
  if (threadIdx.x==0) carry = 0;
  __syncthreads();
  for (int base=0; base<n; base+=256){
    int i = base + threadIdx.x;
    int v = (i<n) ? cnt[i] : 0;
    buf[threadIdx.x] = v;
    __syncthreads();
    for (int off=1; off<256; off<<=1){
      int t = (threadIdx.x>=off) ? buf[threadIdx.x-off] : 0;
      __syncthreads();
      buf[threadIdx.x] += t;
      __syncthreads();
    }
    if (i<n) rp[i] = carry + buf[threadIdx.x] - v;   // exclusive
    int tot = buf[255];
    __syncthreads();
    if (threadIdx.x==0) carry += tot;
    __syncthreads();
  }
  if (threadIdx.x==0) rp[n] = carry;
}

// mode=0: store triple id t; mode=1: store vals[t]
__global__ __launch_bounds__(256) void k_place(const int* __restrict__ rows, const int* __restrict__ vals,
                        const int* __restrict__ rowptr, int* __restrict__ cur, int* __restrict__ idx, int mode){
  int t = blockIdx.x*256 + threadIdx.x;
  if (t < N_TRI){
    int r = rows[t];
    int p = atomicAdd(&cur[r], 1);
    idx[rowptr[r] + p] = mode ? vals[t] : t;
  }
}

// ---------------- fused sparse means + tanh (wave per node) ----------------
__global__ __launch_bounds__(256) void k_feat0(
    const int* __restrict__ rpE, const int* __restrict__ idxE,
    const int* __restrict__ rpR, const int* __restrict__ idxR,
    const float* __restrict__ ent_emb, const float* __restrict__ rel_emb,
    float* __restrict__ out){
  int wave = threadIdx.x>>6, lane = threadIdx.x&63;
  int i = blockIdx.x*4 + wave;
  if (i >= N_NODE) return;
  int bE = rpE[i], eE = rpE[i+1];
  int bR = rpR[i], eR = rpR[i+1];
  float2 aE = {0.f,0.f}, aR = {0.f,0.f};
  for (int k=bE; k<eE; ++k){
    int c = idxE[k];
    float2 v = *(const float2*)(ent_emb + (size_t)c*DIM + lane*2);
    aE.x += v.x; aE.y += v.y;
  }
  for (int k=bR; k<eR; ++k){
    int c = idxR[k];
    float2 v = *(const float2*)(rel_emb + (size_t)c*DIM + lane*2);
    aR.x += v.x; aR.y += v.y;
  }
  float ie = 1.f/fmaxf((float)(eE-bE), 1.f);
  float ir = 1.f/fmaxf((float)(eR-bR), 1.f);
  float2 oE = { tanhf(aE.x*ie), tanhf(aE.y*ie) };
  float2 oR = { tanhf(aR.x*ir), tanhf(aR.y*ir) };
  *(float2*)(out + (size_t)i*OUTD +   0 + lane*2) = oE;
  *(float2*)(out + (size_t)i*OUTD + 384 + lane*2) = oR;
}

// ---------------- tri_rel segment-sum (atomic, contiguous dest) ----------------
__global__ __launch_bounds__(256) void k_triacc(const int* __restrict__ ridx0, const int* __restrict__ ridx1,
                         const float* __restrict__ rval, const float* __restrict__ rel_emb,
                         float* __restrict__ tri){
  int g = blockIdx.x*256 + threadIdx.x;
  int t = g>>7, d = g&127;
  atomicAdd(tri + (size_t)ridx0[t]*DIM + d, rval[t]*rel_emb[(size_t)ridx1[t]*DIM + d]);
}

__global__ __launch_bounds__(256) void k_trinorm(float* __restrict__ tri, const float* __restrict__ attnE,
                                                 const float* __restrict__ attnR, float* __restrict__ att4){
  __shared__ float ak[4][DIM];
  int tid = threadIdx.x;
  for (int idx=tid; idx<4*DIM; idx+=256){
    int k = idx>>7, d = idx&127;
    ak[k][d] = (k<2) ? attnE[k*DIM + d] : attnR[(k-2)*DIM + d];
  }
  __syncthreads();
  int wave = tid>>6, lane = tid&63;
  int t = blockIdx.x*4 + wave;
  if (t >= N_TRI) return;
  float2 v = *(float2*)(tri + (size_t)t*DIM + lane*2);
  float ss = waveSum(v.x*v.x + v.y*v.y);
  float inv = 1.f/fmaxf(sqrtf(ss), 1e-12f);
  v.x *= inv; v.y *= inv;
  *(float2*)(tri + (size_t)t*DIM + lane*2) = v;
#pragma unroll
  for (int k=0;k<4;k++){
    float p = waveSum(v.x*ak[k][lane*2] + v.y*ak[k][lane*2+1]);
    if (lane==0) att4[(size_t)k*N_TRI + t] = p;
  }
}

// ---------------- fused GAT layer (both branches), wave per row ----------------
// softmax over row's incident triples + Householder aggregation + tanh, no atomics.
__global__ __launch_bounds__(256) void k_gat(
    const int* __restrict__ rowptr, const int* __restrict__ idx, const int* __restrict__ cols,
    const float* __restrict__ tri,
    const float* __restrict__ attA, const float* __restrict__ attB,
    float* __restrict__ out, int inA, int outA, int inB, int outB){
  int wave = threadIdx.x>>6, lane = threadIdx.x&63;
  int i = blockIdx.x*4 + wave;
  if (i >= N_NODE) return;
  int beg = rowptr[i], end = rowptr[i+1];
  float2 accA = {0.f,0.f}, accB = {0.f,0.f};
  if (end > beg){
    float mA = -1e30f, mB = -1e30f;
    for (int k=beg+lane; k<end; k+=64){
      int t = idx[k];
      mA = fmaxf(mA, attA[t]); mB = fmaxf(mB, attB[t]);
    }
    mA = waveMax(mA); mB = waveMax(mB);
    float zA = 0.f, zB = 0.f;
    for (int k=beg+lane; k<end; k+=64){
      int t = idx[k];
      zA += expf(attA[t]-mA); zB += expf(attB[t]-mB);
    }
    zA = waveSum(zA); zB = waveSum(zB);
    float izA = 1.f/zA, izB = 1.f/zB;
    for (int k=beg; k<end; ++k){
      int t = idx[k];
      int c = cols[t];
      float2 u  = *(const float2*)(tri + (size_t)t*DIM + lane*2);
      float2 fA = *(const float2*)(out + (size_t)c*OUTD + inA + lane*2);
      float2 fB = *(const float2*)(out + (size_t)c*OUTD + inB + lane*2);
      float dA = waveSum(fA.x*u.x + fA.y*u.y);
      float dB = waveSum(fB.x*u.x + fB.y*u.y);
      float wA = expf(attA[t]-mA)*izA;
      float wB = expf(attB[t]-mB)*izB;
      accA.x += wA*(fA.x - 2.f*dA*u.x); accA.y += wA*(fA.y - 2.f*dA*u.y);
      accB.x += wB*(fB.x - 2.f*dB*u.x); accB.y += wB*(fB.y - 2.f*dB*u.y);
    }
  }
  float2 oA = { tanhf(accA.x), tanhf(accA.y) };
  float2 oB = { tanhf(accB.x), tanhf(accB.y) };
  *(float2*)(out + (size_t)i*OUTD + outA + lane*2) = oA;
  *(float2*)(out + (size_t)i*OUTD + outB + lane*2) = oB;
}

// ---------------- loss prep: pack E into k-blocked swizzled tiles ----------------
__global__ __launch_bounds__(256) void k_packE(const float* __restrict__ out, __bf16* __restrict__ Ep, float* __restrict__ esq){
  int wave = threadIdx.x>>6, lane = threadIdx.x&63;
  int j = blockIdx.x*4 + wave;
  if (j >= EPAD) return;
  int jt = j>>7, r = j&127;
  __bf16* tb = Ep + (size_t)jt*TILE_ELEMS;
  float ss = 0.f;
  for (int c=lane; c<96; c+=64){   // 96 chunks of 8 elements
    int kb = c>>2, q = c&3;
    bf16x8 o;
    if (j < N_NODE){
      const float* src = out + (size_t)j*OUTD + c*8;
#pragma unroll
      for (int e=0;e<8;e++){ float v = src[e]; ss += v*v; o[e] = (__bf16)v; }
    } else {
#pragma unroll
      for (int e=0;e<8;e++) o[e] = (__bf16)0.f;
    }
    *(bf16x8*)(tb + kb*KBLK_ELEMS + swz_off(r, q)) = o;
  }
  ss = waveSum(ss);
  if (lane==0) esq[j] = (j < N_NODE) ? ss : 0.f;
}

__global__ __launch_bounds__(256) void k_packA(const int* __restrict__ pairs, const __bf16* __restrict__ Ep,
    const float* __restrict__ out, const float* __restrict__ esq,
    __bf16* __restrict__ Ap, float* __restrict__ asq, float* __restrict__ pos){
  int wave = threadIdx.x>>6, lane = threadIdx.x&63;
  int p = blockIdx.x*4 + wave;
  if (p >= BATCH) return;
  int l = pairs[2*p], r = pairs[2*p+1];
  float ss = 0.f;
#pragma unroll
  for (int c=0;c<12;c++){
    int d = c*64 + lane;
    float dl = out[(size_t)l*OUTD + d], dr = out[(size_t)r*OUTD + d];
    ss += (dl-dr)*(dl-dr);
  }
  ss = waveSum(ss);
  if (lane==0){ pos[p] = ss; asq[p] = esq[l]; asq[p+BATCH] = esq[r]; }
  int lt = l>>7, lr = l&127;
  int rt2 = r>>7, rr = r&127;
  int p0t = p>>7, p0r = p&127;
  int p1t = (p+BATCH)>>7, p1r = (p+BATCH)&127;
  for (int c=lane; c<96; c+=64){
    int kb = c>>2, q = c&3;
    bf16x8 vl = *(const bf16x8*)(Ep + (size_t)lt*TILE_ELEMS + kb*KBLK_ELEMS + swz_off(lr, q));
    *(bf16x8*)(Ap + (size_t)p0t*TILE_ELEMS + kb*KBLK_ELEMS + swz_off(p0r, q)) = vl;
    bf16x8 vr = *(const bf16x8*)(Ep + (size_t)rt2*TILE_ELEMS + kb*KBLK_ELEMS + swz_off(rr, q));
    *(bf16x8*)(Ap + (size_t)p1t*TILE_ELEMS + kb*KBLK_ELEMS + swz_off(p1r, q)) = vr;
  }
}

// ---------------- fused GEMM + loss (m97 structure) ----------------
__global__ __launch_bounds__(256) void k_gemm_loss(
    const __bf16* __restrict__ Ap, const __bf16* __restrict__ Ep,
    const float* __restrict__ asq, const float* __restrict__ esq,
    const float* __restrict__ pos, const int* __restrict__ pairs,
    float* __restrict__ rsum, float* __restrict__ rsq, float* __restrict__ rmax,
    const float* __restrict__ mu, const float* __restrict__ sd, const float* __restrict__ mm,
    float* __restrict__ rexp, int pass)
{
  __shared__ __bf16 sA[KBLK_ELEMS];
  __shared__ __bf16 sB[KBLK_ELEMS];
  __shared__ float lsum[128], lsq[128], lmax[128];
  int tid = threadIdx.x;
  if (tid < 128){ lsum[tid]=0.f; lsq[tid]=0.f; lmax[tid]=-1e30f; }

  int wave = tid>>6, lane = tid&63, quad = lane>>4, l16 = lane&15;
  int bi = blockIdx.y, bj = blockIdx.x;
  int wi = wave>>1, wj = wave&1;

  const __bf16* Asrc = Ap + (size_t)bi*TILE_ELEMS;
  const __bf16* Bsrc = Ep + (size_t)bj*TILE_ELEMS;

  int a_off[4], b_off[4];
#pragma unroll
  for (int rt=0; rt<4; ++rt){ int row = wi*64 + rt*16 + l16; a_off[rt] = swz_off(row, quad); }
#pragma unroll
  for (int ct=0; ct<4; ++ct){ int row = wj*64 + ct*16 + l16; b_off[ct] = swz_off(row, quad); }

  const __bf16* gsrc = (wave<2 ? Asrc : Bsrc);
  __bf16* ldsb = (wave<2 ? sA : sB);
  int half = (wave&1)*2048;   // elements

  const f32x4 zf = {0.f,0.f,0.f,0.f};
  f32x4 acc[4][4];
#pragma unroll
  for (int rt=0; rt<4; ++rt)
#pragma unroll
    for (int ct=0; ct<4; ++ct) acc[rt][ct] = zf;

  for (int kb=0; kb<24; ++kb){
    __syncthreads();
    const __bf16* g = gsrc + kb*KBLK_ELEMS + half + lane*8;
#pragma unroll
    for (int s=0; s<4; ++s)
      gl2lds16(g + s*512, ldsb + half + s*512);
    __syncthreads();
    bf16x8 af[4], bf[4];
#pragma unroll
    for (int rt=0; rt<4; ++rt) af[rt] = *(const bf16x8*)(sA + a_off[rt]);
#pragma unroll
    for (int ct=0; ct<4; ++ct) bf[ct] = *(const bf16x8*)(sB + b_off[ct]);
#pragma unroll
    for (int rt=0; rt<4; ++rt)
#pragma unroll
      for (int ct=0; ct<4; ++ct)
        acc[rt][ct] = __builtin_amdgcn_mfma_f32_16x16x32_bf16(af[rt], bf[ct], acc[rt][ct], 0,0,0);
  }

  // ---- loss epilogue ----
  int jbase = bj*128 + wj*64;
  float esqv[4]; bool val[4]; int jcol[4];
#pragma unroll
  for (int ct=0; ct<4; ++ct){
    jcol[ct] = jbase + ct*16 + l16;
    val[ct] = jcol[ct] < N_NODE;
    esqv[ct] = esq[jcol[ct]];
  }

#pragma unroll
  for (int rt=0; rt<4; ++rt){
#pragma unroll
    for (int reg=0; reg<4; ++reg){
      int il = wi*64 + rt*16 + quad*4 + reg;
      int i  = bi*128 + il;
      int p  = i & (BATCH-1);
      int li = pairs[2*p], ri = pairs[2*p+1];
      float Kv = pos[p] + GAMMA_C;
      float av = asq[i];
      if (pass == 1){
        float s=0.f, q=0.f, mx=-1e30f;
#pragma unroll
        for (int ct=0; ct<4; ++ct){
          if (val[ct]){
            float neg = av + esqv[ct] - 2.f*acc[rt][ct][reg];
            float fct = 1.f - (jcol[ct]==li ? 1.f:0.f) - (jcol[ct]==ri ? 1.f:0.f);
            float loss = (Kv - neg)*fct;
            float x = loss - Kv;
            s += x; q += x*x; mx = fmaxf(mx, loss);
          }
        }
#pragma unroll
        for (int m=1;m<16;m<<=1){
          s += __shfl_xor(s,m,64); q += __shfl_xor(q,m,64);
          mx = fmaxf(mx, __shfl_xor(mx,m,64));
        }
        if (l16 == 0){
          atomicAdd(&lsum[il], s); atomicAdd(&lsq[il], q); atomicMaxF(&lmax[il], mx);
        }
      } else {
        float muv = mu[i], isd = 1.f/sd[i], Mv = mm[i];
        float s = 0.f;
#pragma unroll
        for (int ct=0; ct<4; ++ct){
          if (val[ct]){
            float neg = av + esqv[ct] - 2.f*acc[rt][ct][reg];
            float fct = 1.f - (jcol[ct]==li ? 1.f:0.f) - (jcol[ct]==ri ? 1.f:0.f);
            float loss = (Kv - neg)*fct;
            s += expf(LAMB_C*(loss-muv)*isd + TAU_C - Mv);
          }
        }
#pragma unroll
        for (int m=1;m<16;m<<=1) s += __shfl_xor(s,m,64);
        if (l16 == 0) atomicAdd(&lsum[il], s);
      }
    }
  }
  __syncthreads();
  if (tid < 128){
    int i = bi*128 + tid;
    if (pass == 1){
      atomicAdd(rsum+i, lsum[tid]); atomicAdd(rsq+i, lsq[tid]); atomicMaxF(rmax+i, lmax[tid]);
    } else {
      atomicAdd(rexp+i, lsum[tid]);
    }
  }
}

__global__ __launch_bounds__(256) void k_stats(const float* __restrict__ rsum, const float* __restrict__ rsq,
                      const float* __restrict__ rmax, const float* __restrict__ pos,
                      float* __restrict__ mu, float* __restrict__ sd, float* __restrict__ mm){
  int i = blockIdx.x*256 + threadIdx.x;
  if (i >= NROWA) return;
  float K = pos[i & (BATCH-1)] + GAMMA_C;
  float a = rsum[i]*(1.f/N_NODE);
  float m = K + a;
  float v = rsq[i]*(1.f/N_NODE) - a*a;
  float s = sqrtf(fmaxf(v, 1e-30f));
  mu[i]=m; sd[i]=s;
  mm[i] = LAMB_C*(rmax[i]-m)/s + TAU_C;
}

__global__ __launch_bounds__(256) void k_final(const float* __restrict__ mm, const float* __restrict__ rexp, float* __restrict__ out){
  __shared__ float red[256];
  float s = 0.f;
  for (int i=threadIdx.x; i<NROWA; i+=256) s += mm[i] + logf(rexp[i]);
  red[threadIdx.x] = s; __syncthreads();
  for (int st=128; st>0; st>>=1){ if (threadIdx.x<st) red[threadIdx.x]+=red[threadIdx.x+st]; __syncthreads(); }
  if (threadIdx.x==0) out[0] = red[0]*(1.f/BATCH);
}

extern "C" void kernel_launch(void* const* d_in, const int* in_sizes, int n_in,
                              void* d_out, int out_size, void* d_ws, size_t ws_size,
                              hipStream_t stream) {
  const int*   pairs   = (const int*)d_in[0];
  const int*   ent_adj = (const int*)d_in[1];
  const int*   rel_adj = (const int*)d_in[2];
  const int*   adj     = (const int*)d_in[3];
  const int*   r_index = (const int*)d_in[4];
  const float* r_val   = (const float*)d_in[5];
  const float* ent_emb = (const float*)d_in[7];
  const float* rel_emb = (const float*)d_in[8];
  const float* attn_e  = (const float*)d_in[9];
  const float* attn_r  = (const float*)d_in[10];

  char* base = (char*)d_ws;
  size_t off = 0;
  auto take = [&](size_t bytes)->char*{
    char* p = base + off;
    off = (off + bytes + 511) & ~(size_t)511;
    return p;
  };
  float* OUT  = (float*)take((size_t)N_NODE*OUTD*4);   // 92.16 MB
  char*  TRIB = take((size_t)N_TRI*DIM*4);             // 102.4 MB, reused after GAT
  float* TRI  = (float*)TRIB;
  float* ATT4 = (float*)take((size_t)4*N_TRI*4);
  // CSR arrays (live through GAT phase)
  int* RP_E  = (int*)take((size_t)(N_NODE+1)*4);
  int* RP_R  = (int*)take((size_t)(N_NODE+1)*4);
  int* RP_A  = (int*)take((size_t)(N_NODE+1)*4);
  int* IDX_E = (int*)take((size_t)N_TRI*4);
  int* IDX_R = (int*)take((size_t)N_TRI*4);
  int* IDX_A = (int*)take((size_t)N_TRI*4);
  int* CNT6  = (int*)take((size_t)6*N_NODE*4);   // cntE,cntR,cntA,curE,curR,curA
  int* CNT_E = CNT6,            *CNT_R = CNT6 + N_NODE,   *CNT_A = CNT6 + 2*N_NODE;
  int* CUR_E = CNT6 + 3*N_NODE, *CUR_R = CNT6 + 4*N_NODE, *CUR_A = CNT6 + 5*N_NODE;

  // overlay on TRI block (dead after GAT layers)
  size_t roff = 0;
  auto take2 = [&](size_t bytes)->char*{
    char* p = TRIB + roff;
    roff = (roff + bytes + 511) & ~(size_t)511;
    return p;
  };
  __bf16* EP    = (__bf16*)take2((size_t)NTILE_E*TILE_ELEMS*2); // 46.2 MB packed E
  float*  ESQ   = (float*)take2((size_t)EPAD*4);
  __bf16* AP    = (__bf16*)take2((size_t)NTILE_A*TILE_ELEMS*2); // 6.3 MB packed A
  float*  ASQ   = (float*)take2((size_t)NROWA*4);
  float*  POS   = (float*)take2((size_t)BATCH*4);
  float*  RSUM  = (float*)take2((size_t)NROWA*4);
  float*  RSQ   = (float*)take2((size_t)NROWA*4);
  float*  RMAX  = (float*)take2((size_t)NROWA*4);
  float*  MU    = (float*)take2((size_t)NROWA*4);
  float*  SD    = (float*)take2((size_t)NROWA*4);
  float*  MM    = (float*)take2((size_t)NROWA*4);
  float*  REXP  = (float*)take2((size_t)NROWA*4);

  // ---- init ----
  k_fill<<<8192,256,0,stream>>>(TRI, (long)N_TRI*DIM, 0.f);
  k_fill<<<192,256,0,stream>>>((float*)CNT6, (long)6*N_NODE, 0.f);  // int zeros

  // ---- CSR builds (ent_adj rows, rel_adj rows, adj rows) ----
  k_hist<<<782,256,0,stream>>>(ent_adj, CNT_E);
  k_hist<<<782,256,0,stream>>>(rel_adj, CNT_R);
  k_hist<<<782,256,0,stream>>>(adj,     CNT_A);
  k_scan3<<<3,256,0,stream>>>(CNT_E, RP_E, CNT_R, RP_R, CNT_A, RP_A, N_NODE);
  k_place<<<782,256,0,stream>>>(ent_adj, ent_adj+N_TRI, RP_E, CUR_E, IDX_E, 1); // store col
  k_place<<<782,256,0,stream>>>(rel_adj, rel_adj+N_TRI, RP_R, CUR_R, IDX_R, 1); // store col
  k_place<<<782,256,0,stream>>>(adj,     (const int*)0, RP_A, CUR_A, IDX_A, 0); // store t

  // ---- fused sparse means + tanh ----
  k_feat0<<<7500,256,0,stream>>>(RP_E, IDX_E, RP_R, IDX_R, ent_emb, rel_emb, OUT);

  // ---- tri_rel + att logits ----
  k_triacc<<<100000,256,0,stream>>>(r_index, r_index+N_TRI, r_val, rel_emb, TRI);
  k_trinorm<<<50000,256,0,stream>>>(TRI, attn_e, attn_r, ATT4);

  // ---- 2 fused GAT layers (e-branch + r-branch together) ----
  k_gat<<<7500,256,0,stream>>>(RP_A, IDX_A, adj+N_TRI, TRI,
                               ATT4 + 0*N_TRI, ATT4 + 2*N_TRI, OUT,
                               0, 128, 384, 512);
  k_gat<<<7500,256,0,stream>>>(RP_A, IDX_A, adj+N_TRI, TRI,
                               ATT4 + 1*N_TRI, ATT4 + 3*N_TRI, OUT,
                               128, 256, 512, 640);

  // ---- loss prep (TRI block now reused) ----
  k_packE<<<7520,256,0,stream>>>(OUT, EP, ESQ);
  k_packA<<<512,256,0,stream>>>(pairs, EP, OUT, ESQ, AP, ASQ, POS);
  k_fill<<<16,256,0,stream>>>(RSUM, (long)NROWA, 0.f);
  k_fill<<<16,256,0,stream>>>(RSQ,  (long)NROWA, 0.f);
  k_fill<<<16,256,0,stream>>>(REXP, (long)NROWA, 0.f);
  k_fill<<<16,256,0,stream>>>(RMAX, (long)NROWA, -1e30f);

  // ---- fused GEMM + loss ----
  dim3 gg(NTILE_E, NTILE_A, 1);  // 235 x 32
  k_gemm_loss<<<gg,256,0,stream>>>(AP, EP, ASQ, ESQ, POS, pairs,
                                   RSUM, RSQ, RMAX, MU, SD, MM, REXP, 1);
  k_stats<<<16,256,0,stream>>>(RSUM, RSQ, RMAX, POS, MU, SD, MM);
  k_gemm_loss<<<gg,256,0,stream>>>(AP, EP, ASQ, ESQ, POS, pairs,
                                   RSUM, RSQ, RMAX, MU, SD, MM, REXP, 2);
  k_final<<<1,256,0,stream>>>(MM, REXP, (float*)d_out);
}

// Round 4
// 1178.810 us; speedup vs baseline: 2.7717x; 1.1275x over previous
//
#include <hip/hip_runtime.h>
#include <hip/hip_bf16.h>
#include <math.h>

#define N_NODE 30000
#define N_TRI  200000
#define DIM    128
#define OUTD   768
#define BATCH  2048
#define NROWA  4096
#define EPAD   30080   // 235*128, padded node count for GEMM tiles
#define NTILE_E 235
#define NTILE_A 32
#define TILE_ELEMS (128*OUTD)     // 98304 elements per 128-row tile
#define KBLK_ELEMS (128*32)       // 4096 elements per (128 x 32) k-block
#define GAMMA_C 3.0f
#define LAMB_C  30.0f
#define TAU_C   10.0f

typedef __attribute__((ext_vector_type(8))) __bf16 bf16x8;
typedef __attribute__((ext_vector_type(4))) float f32x4;

__device__ __forceinline__ float waveSum(float v){
#pragma unroll
  for (int m=1;m<64;m<<=1) v += __shfl_xor(v, m, 64);
  return v;
}
__device__ __forceinline__ float waveMax(float v){
#pragma unroll
  for (int m=1;m<64;m<<=1) v = fmaxf(v, __shfl_xor(v, m, 64));
  return v;
}

__device__ __forceinline__ void atomicMaxF(float* a, float v){
  if (v >= 0.f) atomicMax((int*)a, __float_as_int(v));
  else          atomicMin((unsigned int*)a, __float_as_uint(v));
}

__device__ __forceinline__ void gl2lds16(const void* g, void* l){
  __builtin_amdgcn_global_load_lds(
      (const __attribute__((address_space(1))) char*)g,
      (__attribute__((address_space(3))) char*)l, 16, 0, 0);
}

// swizzled 16B-chunk offset inside a (128 x 32) k-block: row r (0..127), logical chunk q (0..3)
__device__ __forceinline__ int swz_off(int r, int q){
  return r*32 + ((q ^ ((r>>1)&3))<<3);
}

// ---------------- fill ----------------
__global__ void k_fill(float* __restrict__ p, long n, float v){
  long i = (long)blockIdx.x*blockDim.x + threadIdx.x;
  long st = (long)gridDim.x*blockDim.x;
  for (; i<n; i+=st) p[i]=v;
}

// ---------------- CSR build ----------------
__global__ __launch_bounds__(256) void k_hist(const int* __restrict__ rows, int* __restrict__ cnt){
  int t = blockIdx.x*256 + threadIdx.x;
  if (t < N_TRI) atomicAdd(&cnt[rows[t]], 1);
}

// one block per (cnt,rowptr) pair; exclusive scan of n=30000 + total at rowptr[n]
__global__ __launch_bounds__(256) void k_scan3(
    const int* __restrict__ c0, int* __restrict__ r0,
    const int* __restrict__ c1, int* __restrict__ r1,
    const int* __restrict__ c2, int* __restrict__ r2, int n){
  const int* cnt = blockIdx.x==0 ? c0 : (blockIdx.x==1 ? c1 : c2);
  int* rp        = blockIdx.x==0 ? r0 : (blockIdx.x==1 ? r1 : r2);
  __shared__ int buf[256];
  __shared__ int carry;
  if (threadIdx.x==0) carry = 0;
  __syncthreads();
  for (int base=0; base<n; base+=256){
    int i = base + threadIdx.x;
    int v = (i<n) ? cnt[i] : 0;
    buf[threadIdx.x] = v;
    __syncthreads();
    for (int off=1; off<256; off<<=1){
      int t = (threadIdx.x>=off) ? buf[threadIdx.x-off] : 0;
      __syncthreads();
      buf[threadIdx.x] += t;
      __syncthreads();
    }
    if (i<n) rp[i] = carry + buf[threadIdx.x] - v;   // exclusive
    int tot = buf[255];
    __syncthreads();
    if (threadIdx.x==0) carry += tot;
    __syncthreads();
  }
  if (threadIdx.x==0) rp[n] = carry;
}

// mode=0: store triple id t; mode=1: store vals[t]
__global__ __launch_bounds__(256) void k_place(const int* __restrict__ rows, const int* __restrict__ vals,
                        const int* __restrict__ rowptr, int* __restrict__ cur, int* __restrict__ idx, int mode){
  int t = blockIdx.x*256 + threadIdx.x;
  if (t < N_TRI){
    int r = rows[t];
    int p = atomicAdd(&cur[r], 1);
    idx[rowptr[r] + p] = mode ? vals[t] : t;
  }
}

// ---------------- fused sparse means + tanh (wave per node) ----------------
__global__ __launch_bounds__(256) void k_feat0(
    const int* __restrict__ rpE, const int* __restrict__ idxE,
    const int* __restrict__ rpR, const int* __restrict__ idxR,
    const float* __restrict__ ent_emb, const float* __restrict__ rel_emb,
    float* __restrict__ out){
  int wave = threadIdx.x>>6, lane = threadIdx.x&63;
  int i = blockIdx.x*4 + wave;
  if (i >= N_NODE) return;
  int bE = rpE[i], eE = rpE[i+1];
  int bR = rpR[i], eR = rpR[i+1];
  float2 aE = {0.f,0.f}, aR = {0.f,0.f};
  for (int k=bE; k<eE; ++k){
    int c = idxE[k];
    float2 v = *(const float2*)(ent_emb + (size_t)c*DIM + lane*2);
    aE.x += v.x; aE.y += v.y;
  }
  for (int k=bR; k<eR; ++k){
    int c = idxR[k];
    float2 v = *(const float2*)(rel_emb + (size_t)c*DIM + lane*2);
    aR.x += v.x; aR.y += v.y;
  }
  float ie = 1.f/fmaxf((float)(eE-bE), 1.f);
  float ir = 1.f/fmaxf((float)(eR-bR), 1.f);
  float2 oE = { tanhf(aE.x*ie), tanhf(aE.y*ie) };
  float2 oR = { tanhf(aR.x*ir), tanhf(aR.y*ir) };
  *(float2*)(out + (size_t)i*OUTD +   0 + lane*2) = oE;
  *(float2*)(out + (size_t)i*OUTD + 384 + lane*2) = oR;
}

// ---------------- tri_rel direct (r_index[0] == arange) + norm + att logits ----------------
// tri_rel[t] = normalize(r_val[t] * rel_emb[ridx1[t]]); att4[k][t] = tri_rel[t] . ak[k]
__global__ __launch_bounds__(256) void k_trinorm(
    const int* __restrict__ ridx1, const float* __restrict__ rval,
    const float* __restrict__ rel_emb,
    float* __restrict__ tri, const float* __restrict__ attnE,
    const float* __restrict__ attnR, float* __restrict__ att4){
  __shared__ float ak[4][DIM];
  int tid = threadIdx.x;
  for (int idx=tid; idx<4*DIM; idx+=256){
    int k = idx>>7, d = idx&127;
    ak[k][d] = (k<2) ? attnE[k*DIM + d] : attnR[(k-2)*DIM + d];
  }
  __syncthreads();
  int wave = tid>>6, lane = tid&63;
  int t = blockIdx.x*4 + wave;
  if (t >= N_TRI) return;
  int rr = ridx1[t];
  float rv = rval[t];
  float2 v = *(const float2*)(rel_emb + (size_t)rr*DIM + lane*2);
  v.x *= rv; v.y *= rv;
  float ss = waveSum(v.x*v.x + v.y*v.y);
  float inv = 1.f/fmaxf(sqrtf(ss), 1e-12f);
  v.x *= inv; v.y *= inv;
  *(float2*)(tri + (size_t)t*DIM + lane*2) = v;
#pragma unroll
  for (int k=0;k<4;k++){
    float p = waveSum(v.x*ak[k][lane*2] + v.y*ak[k][lane*2+1]);
    if (lane==0) att4[(size_t)k*N_TRI + t] = p;
  }
}

// ---------------- fused GAT layer (both branches), wave per row ----------------
__global__ __launch_bounds__(256) void k_gat(
    const int* __restrict__ rowptr, const int* __restrict__ idx, const int* __restrict__ cols,
    const float* __restrict__ tri,
    const float* __restrict__ attA, const float* __restrict__ attB,
    float* __restrict__ out, int inA, int outA, int inB, int outB){
  int wave = threadIdx.x>>6, lane = threadIdx.x&63;
  int i = blockIdx.x*4 + wave;
  if (i >= N_NODE) return;
  int beg = rowptr[i], end = rowptr[i+1];
  float2 accA = {0.f,0.f}, accB = {0.f,0.f};
  if (end > beg){
    float mA = -1e30f, mB = -1e30f;
    for (int k=beg+lane; k<end; k+=64){
      int t = idx[k];
      mA = fmaxf(mA, attA[t]); mB = fmaxf(mB, attB[t]);
    }
    mA = waveMax(mA); mB = waveMax(mB);
    float zA = 0.f, zB = 0.f;
    for (int k=beg+lane; k<end; k+=64){
      int t = idx[k];
      zA += expf(attA[t]-mA); zB += expf(attB[t]-mB);
    }
    zA = waveSum(zA); zB = waveSum(zB);
    float izA = 1.f/zA, izB = 1.f/zB;
    for (int k=beg; k<end; ++k){
      int t = idx[k];
      int c = cols[t];
      float2 u  = *(const float2*)(tri + (size_t)t*DIM + lane*2);
      float2 fA = *(const float2*)(out + (size_t)c*OUTD + inA + lane*2);
      float2 fB = *(const float2*)(out + (size_t)c*OUTD + inB + lane*2);
      float dA = waveSum(fA.x*u.x + fA.y*u.y);
      float dB = waveSum(fB.x*u.x + fB.y*u.y);
      float wA = expf(attA[t]-mA)*izA;
      float wB = expf(attB[t]-mB)*izB;
      accA.x += wA*(fA.x - 2.f*dA*u.x); accA.y += wA*(fA.y - 2.f*dA*u.y);
      accB.x += wB*(fB.x - 2.f*dB*u.x); accB.y += wB*(fB.y - 2.f*dB*u.y);
    }
  }
  float2 oA = { tanhf(accA.x), tanhf(accA.y) };
  float2 oB = { tanhf(accB.x), tanhf(accB.y) };
  *(float2*)(out + (size_t)i*OUTD + outA + lane*2) = oA;
  *(float2*)(out + (size_t)i*OUTD + outB + lane*2) = oB;
}

// ---------------- loss prep: pack E into k-blocked swizzled tiles ----------------
__global__ __launch_bounds__(256) void k_packE(const float* __restrict__ out, __bf16* __restrict__ Ep, float* __restrict__ esq){
  int wave = threadIdx.x>>6, lane = threadIdx.x&63;
  int j = blockIdx.x*4 + wave;
  if (j >= EPAD) return;
  int jt = j>>7, r = j&127;
  __bf16* tb = Ep + (size_t)jt*TILE_ELEMS;
  float ss = 0.f;
  for (int c=lane; c<96; c+=64){   // 96 chunks of 8 elements
    int kb = c>>2, q = c&3;
    bf16x8 o;
    if (j < N_NODE){
      const float* src = out + (size_t)j*OUTD + c*8;
#pragma unroll
      for (int e=0;e<8;e++){ float v = src[e]; ss += v*v; o[e] = (__bf16)v; }
    } else {
#pragma unroll
      for (int e=0;e<8;e++) o[e] = (__bf16)0.f;
    }
    *(bf16x8*)(tb + kb*KBLK_ELEMS + swz_off(r, q)) = o;
  }
  ss = waveSum(ss);
  if (lane==0) esq[j] = (j < N_NODE) ? ss : 0.f;
}

__global__ __launch_bounds__(256) void k_packA(const int* __restrict__ pairs, const __bf16* __restrict__ Ep,
    const float* __restrict__ out, const float* __restrict__ esq,
    __bf16* __restrict__ Ap, float* __restrict__ asq, float* __restrict__ pos){
  int wave = threadIdx.x>>6, lane = threadIdx.x&63;
  int p = blockIdx.x*4 + wave;
  if (p >= BATCH) return;
  int l = pairs[2*p], r = pairs[2*p+1];
  float ss = 0.f;
#pragma unroll
  for (int c=0;c<12;c++){
    int d = c*64 + lane;
    float dl = out[(size_t)l*OUTD + d], dr = out[(size_t)r*OUTD + d];
    ss += (dl-dr)*(dl-dr);
  }
  ss = waveSum(ss);
  if (lane==0){ pos[p] = ss; asq[p] = esq[l]; asq[p+BATCH] = esq[r]; }
  int lt = l>>7, lr = l&127;
  int rt2 = r>>7, rr = r&127;
  int p0t = p>>7, p0r = p&127;
  int p1t = (p+BATCH)>>7, p1r = (p+BATCH)&127;
  for (int c=lane; c<96; c+=64){
    int kb = c>>2, q = c&3;
    bf16x8 vl = *(const bf16x8*)(Ep + (size_t)lt*TILE_ELEMS + kb*KBLK_ELEMS + swz_off(lr, q));
    *(bf16x8*)(Ap + (size_t)p0t*TILE_ELEMS + kb*KBLK_ELEMS + swz_off(p0r, q)) = vl;
    bf16x8 vr = *(const bf16x8*)(Ep + (size_t)rt2*TILE_ELEMS + kb*KBLK_ELEMS + swz_off(rr, q));
    *(bf16x8*)(Ap + (size_t)p1t*TILE_ELEMS + kb*KBLK_ELEMS + swz_off(p1r, q)) = vr;
  }
}

// ---------------- fused GEMM + loss (m97 structure) ----------------
// grid: x = bi (32 A-tiles, fast) so all blocks sharing an EP tile are dispatch-adjacent;
// y = bj (235 E-tiles, slow). EP fetched ~once from HBM; AP stays cache-resident.
__global__ __launch_bounds__(256) void k_gemm_loss(
    const __bf16* __restrict__ Ap, const __bf16* __restrict__ Ep,
    const float* __restrict__ asq, const float* __restrict__ esq,
    const float* __restrict__ pos, const int* __restrict__ pairs,
    float* __restrict__ rsum, float* __restrict__ rsq, float* __restrict__ rmax,
    const float* __restrict__ mu, const float* __restrict__ sd, const float* __restrict__ mm,
    float* __restrict__ rexp, int pass)
{
  __shared__ __bf16 sA[KBLK_ELEMS];
  __shared__ __bf16 sB[KBLK_ELEMS];
  __shared__ float lsum[128], lsq[128], lmax[128];
  int tid = threadIdx.x;
  if (tid < 128){ lsum[tid]=0.f; lsq[tid]=0.f; lmax[tid]=-1e30f; }

  int wave = tid>>6, lane = tid&63, quad = lane>>4, l16 = lane&15;
  int bi = blockIdx.x, bj = blockIdx.y;
  int wi = wave>>1, wj = wave&1;

  const __bf16* Asrc = Ap + (size_t)bi*TILE_ELEMS;
  const __bf16* Bsrc = Ep + (size_t)bj*TILE_ELEMS;

  int a_off[4], b_off[4];
#pragma unroll
  for (int rt=0; rt<4; ++rt){ int row = wi*64 + rt*16 + l16; a_off[rt] = swz_off(row, quad); }
#pragma unroll
  for (int ct=0; ct<4; ++ct){ int row = wj*64 + ct*16 + l16; b_off[ct] = swz_off(row, quad); }

  const __bf16* gsrc = (wave<2 ? Asrc : Bsrc);
  __bf16* ldsb = (wave<2 ? sA : sB);
  int half = (wave&1)*2048;   // elements

  const f32x4 zf = {0.f,0.f,0.f,0.f};
  f32x4 acc[4][4];
#pragma unroll
  for (int rt=0; rt<4; ++rt)
#pragma unroll
    for (int ct=0; ct<4; ++ct) acc[rt][ct] = zf;

  for (int kb=0; kb<24; ++kb){
    __syncthreads();
    const __bf16* g = gsrc + kb*KBLK_ELEMS + half + lane*8;
#pragma unroll
    for (int s=0; s<4; ++s)
      gl2lds16(g + s*512, ldsb + half + s*512);
    __syncthreads();
    bf16x8 af[4], bf[4];
#pragma unroll
    for (int rt=0; rt<4; ++rt) af[rt] = *(const bf16x8*)(sA + a_off[rt]);
#pragma unroll
    for (int ct=0; ct<4; ++ct) bf[ct] = *(const bf16x8*)(sB + b_off[ct]);
#pragma unroll
    for (int rt=0; rt<4; ++rt)
#pragma unroll
      for (int ct=0; ct<4; ++ct)
        acc[rt][ct] = __builtin_amdgcn_mfma_f32_16x16x32_bf16(af[rt], bf[ct], acc[rt][ct], 0,0,0);
  }

  // ---- loss epilogue ----
  int jbase = bj*128 + wj*64;
  float esqv[4]; bool val[4]; int jcol[4];
#pragma unroll
  for (int ct=0; ct<4; ++ct){
    jcol[ct] = jbase + ct*16 + l16;
    val[ct] = jcol[ct] < N_NODE;
    esqv[ct] = esq[jcol[ct]];
  }

#pragma unroll
  for (int rt=0; rt<4; ++rt){
#pragma unroll
    for (int reg=0; reg<4; ++reg){
      int il = wi*64 + rt*16 + quad*4 + reg;
      int i  = bi*128 + il;
      int p  = i & (BATCH-1);
      int li = pairs[2*p], ri = pairs[2*p+1];
      float Kv = pos[p] + GAMMA_C;
      float av = asq[i];
      if (pass == 1){
        float s=0.f, q=0.f, mx=-1e30f;
#pragma unroll
        for (int ct=0; ct<4; ++ct){
          if (val[ct]){
            float neg = av + esqv[ct] - 2.f*acc[rt][ct][reg];
            float fct = 1.f - (jcol[ct]==li ? 1.f:0.f) - (jcol[ct]==ri ? 1.f:0.f);
            float loss = (Kv - neg)*fct;
            float x = loss - Kv;
            s += x; q += x*x; mx = fmaxf(mx, loss);
          }
        }
#pragma unroll
        for (int m=1;m<16;m<<=1){
          s += __shfl_xor(s,m,64); q += __shfl_xor(q,m,64);
          mx = fmaxf(mx, __shfl_xor(mx,m,64));
        }
        if (l16 == 0){
          atomicAdd(&lsum[il], s); atomicAdd(&lsq[il], q); atomicMaxF(&lmax[il], mx);
        }
      } else {
        float muv = mu[i], isd = 1.f/sd[i], Mv = mm[i];
        float s = 0.f;
#pragma unroll
        for (int ct=0; ct<4; ++ct){
          if (val[ct]){
            float neg = av + esqv[ct] - 2.f*acc[rt][ct][reg];
            float fct = 1.f - (jcol[ct]==li ? 1.f:0.f) - (jcol[ct]==ri ? 1.f:0.f);
            float loss = (Kv - neg)*fct;
            s += expf(LAMB_C*(loss-muv)*isd + TAU_C - Mv);
          }
        }
#pragma unroll
        for (int m=1;m<16;m<<=1) s += __shfl_xor(s,m,64);
        if (l16 == 0) atomicAdd(&lsum[il], s);
      }
    }
  }
  __syncthreads();
  if (tid < 128){
    int i = bi*128 + tid;
    if (pass == 1){
      atomicAdd(rsum+i, lsum[tid]); atomicAdd(rsq+i, lsq[tid]); atomicMaxF(rmax+i, lmax[tid]);
    } else {
      atomicAdd(rexp+i, lsum[tid]);
    }
  }
}

__global__ __launch_bounds__(256) void k_stats(const float* __restrict__ rsum, const float* __restrict__ rsq,
                      const float* __restrict__ rmax, const float* __restrict__ pos,
                      float* __restrict__ mu, float* __restrict__ sd, float* __restrict__ mm){
  int i = blockIdx.x*256 + threadIdx.x;
  if (i >= NROWA) return;
  float K = pos[i & (BATCH-1)] + GAMMA_C;
  float a = rsum[i]*(1.f/N_NODE);
  float m = K + a;
  float v = rsq[i]*(1.f/N_NODE) - a*a;
  float s = sqrtf(fmaxf(v, 1e-30f));
  mu[i]=m; sd[i]=s;
  mm[i] = LAMB_C*(rmax[i]-m)/s + TAU_C;
}

__global__ __launch_bounds__(256) void k_final(const float* __restrict__ mm, const float* __restrict__ rexp, float* __restrict__ out){
  __shared__ float red[256];
  float s = 0.f;
  for (int i=threadIdx.x; i<NROWA; i+=256) s += mm[i] + logf(rexp[i]);
  red[threadIdx.x] = s; __syncthreads();
  for (int st=128; st>0; st>>=1){ if (threadIdx.x<st) red[threadIdx.x]+=red[threadIdx.x+st]; __syncthreads(); }
  if (threadIdx.x==0) out[0] = red[0]*(1.f/BATCH);
}

extern "C" void kernel_launch(void* const* d_in, const int* in_sizes, int n_in,
                              void* d_out, int out_size, void* d_ws, size_t ws_size,
                              hipStream_t stream) {
  const int*   pairs   = (const int*)d_in[0];
  const int*   ent_adj = (const int*)d_in[1];
  const int*   rel_adj = (const int*)d_in[2];
  const int*   adj     = (const int*)d_in[3];
  const int*   r_index = (const int*)d_in[4];
  const float* r_val   = (const float*)d_in[5];
  const float* ent_emb = (const float*)d_in[7];
  const float* rel_emb = (const float*)d_in[8];
  const float* attn_e  = (const float*)d_in[9];
  const float* attn_r  = (const float*)d_in[10];

  char* base = (char*)d_ws;
  size_t off = 0;
  auto take = [&](size_t bytes)->char*{
    char* p = base + off;
    off = (off + bytes + 511) & ~(size_t)511;
    return p;
  };
  float* OUT  = (float*)take((size_t)N_NODE*OUTD*4);   // 92.16 MB
  char*  TRIB = take((size_t)N_TRI*DIM*4);             // 102.4 MB, reused after GAT
  float* TRI  = (float*)TRIB;
  float* ATT4 = (float*)take((size_t)4*N_TRI*4);
  // CSR arrays (live through GAT phase)
  int* RP_E  = (int*)take((size_t)(N_NODE+1)*4);
  int* RP_R  = (int*)take((size_t)(N_NODE+1)*4);
  int* RP_A  = (int*)take((size_t)(N_NODE+1)*4);
  int* IDX_E = (int*)take((size_t)N_TRI*4);
  int* IDX_R = (int*)take((size_t)N_TRI*4);
  int* IDX_A = (int*)take((size_t)N_TRI*4);
  int* CNT6  = (int*)take((size_t)6*N_NODE*4);   // cntE,cntR,cntA,curE,curR,curA
  int* CNT_E = CNT6,            *CNT_R = CNT6 + N_NODE,   *CNT_A = CNT6 + 2*N_NODE;
  int* CUR_E = CNT6 + 3*N_NODE, *CUR_R = CNT6 + 4*N_NODE, *CUR_A = CNT6 + 5*N_NODE;

  // overlay on TRI block (dead after GAT layers)
  size_t roff = 0;
  auto take2 = [&](size_t bytes)->char*{
    char* p = TRIB + roff;
    roff = (roff + bytes + 511) & ~(size_t)511;
    return p;
  };
  __bf16* EP    = (__bf16*)take2((size_t)NTILE_E*TILE_ELEMS*2); // 46.2 MB packed E
  float*  ESQ   = (float*)take2((size_t)EPAD*4);
  __bf16* AP    = (__bf16*)take2((size_t)NTILE_A*TILE_ELEMS*2); // 6.3 MB packed A
  float*  ASQ   = (float*)take2((size_t)NROWA*4);
  float*  POS   = (float*)take2((size_t)BATCH*4);
  float*  RSUM  = (float*)take2((size_t)NROWA*4);
  float*  RSQ   = (float*)take2((size_t)NROWA*4);
  float*  RMAX  = (float*)take2((size_t)NROWA*4);
  float*  MU    = (float*)take2((size_t)NROWA*4);
  float*  SD    = (float*)take2((size_t)NROWA*4);
  float*  MM    = (float*)take2((size_t)NROWA*4);
  float*  REXP  = (float*)take2((size_t)NROWA*4);

  // ---- init ----
  k_fill<<<192,256,0,stream>>>((float*)CNT6, (long)6*N_NODE, 0.f);  // int zeros

  // ---- CSR builds (ent_adj rows, rel_adj rows, adj rows) ----
  k_hist<<<782,256,0,stream>>>(ent_adj, CNT_E);
  k_hist<<<782,256,0,stream>>>(rel_adj, CNT_R);
  k_hist<<<782,256,0,stream>>>(adj,     CNT_A);
  k_scan3<<<3,256,0,stream>>>(CNT_E, RP_E, CNT_R, RP_R, CNT_A, RP_A, N_NODE);
  k_place<<<782,256,0,stream>>>(ent_adj, ent_adj+N_TRI, RP_E, CUR_E, IDX_E, 1); // store col
  k_place<<<782,256,0,stream>>>(rel_adj, rel_adj+N_TRI, RP_R, CUR_R, IDX_R, 1); // store col
  k_place<<<782,256,0,stream>>>(adj,     (const int*)0, RP_A, CUR_A, IDX_A, 0); // store t

  // ---- fused sparse means + tanh ----
  k_feat0<<<7500,256,0,stream>>>(RP_E, IDX_E, RP_R, IDX_R, ent_emb, rel_emb, OUT);

  // ---- tri_rel (direct: r_index[0]==arange) + att logits ----
  k_trinorm<<<50000,256,0,stream>>>(r_index+N_TRI, r_val, rel_emb, TRI, attn_e, attn_r, ATT4);

  // ---- 2 fused GAT layers (e-branch + r-branch together) ----
  k_gat<<<7500,256,0,stream>>>(RP_A, IDX_A, adj+N_TRI, TRI,
                               ATT4 + 0*N_TRI, ATT4 + 2*N_TRI, OUT,
                               0, 128, 384, 512);
  k_gat<<<7500,256,0,stream>>>(RP_A, IDX_A, adj+N_TRI, TRI,
                               ATT4 + 1*N_TRI, ATT4 + 3*N_TRI, OUT,
                               128, 256, 512, 640);

  // ---- loss prep (TRI block now reused) ----
  k_packE<<<7520,256,0,stream>>>(OUT, EP, ESQ);
  k_packA<<<512,256,0,stream>>>(pairs, EP, OUT, ESQ, AP, ASQ, POS);
  k_fill<<<16,256,0,stream>>>(RSUM, (long)NROWA, 0.f);
  k_fill<<<16,256,0,stream>>>(RSQ,  (long)NROWA, 0.f);
  k_fill<<<16,256,0,stream>>>(REXP, (long)NROWA, 0.f);
  k_fill<<<16,256,0,stream>>>(RMAX, (long)NROWA, -1e30f);

  // ---- fused GEMM + loss ----
  dim3 gg(NTILE_A, NTILE_E, 1);  // x = bi (32, fast), y = bj (235, slow)
  k_gemm_loss<<<gg,256,0,stream>>>(AP, EP, ASQ, ESQ, POS, pairs,
                                   RSUM, RSQ, RMAX, MU, SD, MM, REXP, 1);
  k_stats<<<16,256,0,stream>>>(RSUM, RSQ, RMAX, POS, MU, SD, MM);
  k_gemm_loss<<<gg,256,0,stream>>>(AP, EP, ASQ, ESQ, POS, pairs,
                                   RSUM, RSQ, RMAX, MU, SD, MM, REXP, 2);
  k_final<<<1,256,0,stream>>>(MM, REXP, (float*)d_out);
}